// Round 1
// baseline (303.419 us; speedup 1.0000x reference)
//
#include <hip/hip_runtime.h>

#define FUZZ 2187
#define NFEAT 7
#define MID 512
#define NCLS 10
#define BATCH 4096
#define SSTR 2192   // padded row stride for S/G (21 rows each)

// ---------------------------------------------------------------------------
// Kernel 1: S[jm][n] = sum over k with IDX[k,j]==m of wei[k*7+j, n]
// wei is (15309, 2187) row-major. Each thread owns one column n and a k-chunk
// of 27, accumulating 21 partials in registers, then atomicAdd into S.
// Grid: (9 n-tiles of 256, 81 k-chunks). Memory-bound: reads 134 MB once.
// ---------------------------------------------------------------------------
__global__ __launch_bounds__(256) void k_reduce_wei(const float* __restrict__ wei,
                                                    float* __restrict__ S) {
    int n = blockIdx.x * 256 + threadIdx.x;
    if (n >= FUZZ) return;
    float acc[21];
#pragma unroll
    for (int t = 0; t < 21; ++t) acc[t] = 0.f;
    int k0 = blockIdx.y * 27;
    for (int kk = 0; kk < 27; ++kk) {
        int k = k0 + kk;
        int t = k;
        int d[7];
        d[6] = t % 3; t /= 3;
        d[5] = t % 3; t /= 3;
        d[4] = t % 3; t /= 3;
        d[3] = t % 3; t /= 3;
        d[2] = t % 3; t /= 3;
        d[1] = t % 3; t /= 3;
        d[0] = t;                      // k < 2187 so top digit = t
        const float* rowp = wei + (size_t)(k * 7) * FUZZ + n;
#pragma unroll
        for (int j = 0; j < 7; ++j) {
            float v = rowp[(size_t)j * FUZZ];
            int m = d[j];
            acc[j * 3 + 0] += (m == 0) ? v : 0.f;
            acc[j * 3 + 1] += (m == 1) ? v : 0.f;
            acc[j * 3 + 2] += (m == 2) ? v : 0.f;
        }
    }
#pragma unroll
    for (int t = 0; t < 21; ++t)
        atomicAdd(&S[t * SSTR + n], acc[t]);
}

__device__ __forceinline__ float wave_sum(float v) {
#pragma unroll
    for (int off = 32; off > 0; off >>= 1) v += __shfl_down(v, off, 64);
    return v;
}

// ---------------------------------------------------------------------------
// Kernel 2: SW1[jm][i] = sum_n S[jm,n]*W1[i,n];  ws1[i] = sum_n W1[i,n]
// One wave per i (512 blocks). W1 is (512, 2187) row-major.
// ---------------------------------------------------------------------------
__global__ __launch_bounds__(64) void k_sw1(const float* __restrict__ S,
                                            const float* __restrict__ W1,
                                            float* __restrict__ SW1,
                                            float* __restrict__ ws1) {
    int i = blockIdx.x;
    int lane = threadIdx.x;
    float acc[21];
    float aw = 0.f;
#pragma unroll
    for (int t = 0; t < 21; ++t) acc[t] = 0.f;
    for (int n = lane; n < FUZZ; n += 64) {
        float w1 = W1[(size_t)i * FUZZ + n];
        aw += w1;
#pragma unroll
        for (int t = 0; t < 21; ++t) acc[t] += S[t * SSTR + n] * w1;
    }
#pragma unroll
    for (int t = 0; t < 21; ++t) acc[t] = wave_sum(acc[t]);
    aw = wave_sum(aw);
    if (lane == 0) {
#pragma unroll
        for (int t = 0; t < 21; ++t) SW1[t * MID + i] = acc[t];
        ws1[i] = aw;
    }
}

// ---------------------------------------------------------------------------
// Kernel 3: G[jm][n] = sum_i SW1[jm,i]*W2[n,i];  q[n] = sum_i ws1[i]*W2[n,i];
//           p[n] = sum_i b1[i]*W2[n,i].   One wave per n (2187 blocks).
// W2 is (2187, 512) row-major.
// ---------------------------------------------------------------------------
__global__ __launch_bounds__(64) void k_g(const float* __restrict__ SW1,
                                          const float* __restrict__ ws1,
                                          const float* __restrict__ b1,
                                          const float* __restrict__ W2,
                                          float* __restrict__ G,
                                          float* __restrict__ q,
                                          float* __restrict__ p) {
    int n = blockIdx.x;
    int lane = threadIdx.x;
    float acc[21];
    float aq = 0.f, ap = 0.f;
#pragma unroll
    for (int t = 0; t < 21; ++t) acc[t] = 0.f;
    for (int i = lane; i < MID; i += 64) {
        float w2 = W2[(size_t)n * MID + i];
        aq += ws1[i] * w2;
        ap += b1[i] * w2;
#pragma unroll
        for (int t = 0; t < 21; ++t) acc[t] += SW1[t * MID + i] * w2;
    }
#pragma unroll
    for (int t = 0; t < 21; ++t) acc[t] = wave_sum(acc[t]);
    aq = wave_sum(aq);
    ap = wave_sum(ap);
    if (lane == 0) {
#pragma unroll
        for (int t = 0; t < 21; ++t) G[t * SSTR + n] = acc[t];
        q[n] = aq;
        p[n] = ap;
    }
}

// ---------------------------------------------------------------------------
// Kernel 4: H[jm][c] = sum_n (S+G)[jm,n]*W3[c,n]
//           v[c] = sum_n (1+q[n])*W3[c,n]
//           w[c] = sum_n (p[n]+b2[n])*W3[c,n] + b3[c]
//           T[jm] = sum_n S[jm,n]              (block 10)
// Grid: 11 waves. W3 is (10, 2187) row-major.
// ---------------------------------------------------------------------------
__global__ __launch_bounds__(64) void k_h(const float* __restrict__ S,
                                          const float* __restrict__ G,
                                          const float* __restrict__ q,
                                          const float* __restrict__ p,
                                          const float* __restrict__ b2,
                                          const float* __restrict__ b3,
                                          const float* __restrict__ W3,
                                          float* __restrict__ H,
                                          float* __restrict__ v,
                                          float* __restrict__ w,
                                          float* __restrict__ T) {
    int c = blockIdx.x;
    int lane = threadIdx.x;
    if (c < NCLS) {
        float acc[21];
        float av = 0.f, aw = 0.f;
#pragma unroll
        for (int t = 0; t < 21; ++t) acc[t] = 0.f;
        for (int n = lane; n < FUZZ; n += 64) {
            float w3 = W3[(size_t)c * FUZZ + n];
            av += (1.0f + q[n]) * w3;
            aw += (p[n] + b2[n]) * w3;
#pragma unroll
            for (int t = 0; t < 21; ++t)
                acc[t] += (S[t * SSTR + n] + G[t * SSTR + n]) * w3;
        }
#pragma unroll
        for (int t = 0; t < 21; ++t) acc[t] = wave_sum(acc[t]);
        av = wave_sum(av);
        aw = wave_sum(aw);
        if (lane == 0) {
#pragma unroll
            for (int t = 0; t < 21; ++t) H[t * NCLS + c] = acc[t];
            v[c] = av;
            w[c] = aw + b3[c];
        }
    } else {
        float acc[21];
#pragma unroll
        for (int t = 0; t < 21; ++t) acc[t] = 0.f;
        for (int n = lane; n < FUZZ; n += 64) {
#pragma unroll
            for (int t = 0; t < 21; ++t) acc[t] += S[t * SSTR + n];
        }
#pragma unroll
        for (int t = 0; t < 21; ++t) acc[t] = wave_sum(acc[t]);
        if (lane == 0) {
#pragma unroll
            for (int t = 0; t < 21; ++t) T[t] = acc[t];
        }
    }
}

// ---------------------------------------------------------------------------
// Kernel 5: per-batch epilogue.
// u[j,m] = exp(-(x[b,j]-c[j,m])^2 / b[j,m]^2)
// r = 2187*bais + sum u*T
// out[b,c] = leaky_relu( (sum_jm u*H[jm,c] + bais*v[c]) / r + w[c], 0.2 )
// ---------------------------------------------------------------------------
__global__ __launch_bounds__(256) void k_out(const float* __restrict__ x,
                                             const float* __restrict__ cc,
                                             const float* __restrict__ bbv,
                                             const float* __restrict__ bais,
                                             const float* __restrict__ T,
                                             const float* __restrict__ H,
                                             const float* __restrict__ v,
                                             const float* __restrict__ w,
                                             float* __restrict__ out) {
    int b = blockIdx.x * 256 + threadIdx.x;
    if (b >= BATCH) return;
    float xv[NFEAT];
#pragma unroll
    for (int j = 0; j < NFEAT; ++j) xv[j] = x[b * NFEAT + j];
    float u[21];
#pragma unroll
    for (int j = 0; j < NFEAT; ++j) {
#pragma unroll
        for (int m = 0; m < 3; ++m) {
            float d = xv[j] - cc[j * 3 + m];
            float bv = bbv[j * 3 + m];
            u[j * 3 + m] = expf(-(d * d) / (bv * bv));
        }
    }
    float ba = bais[0];
    float r = 2187.0f * ba;
#pragma unroll
    for (int t = 0; t < 21; ++t) r += u[t] * T[t];
    float inv = 1.0f / r;
#pragma unroll
    for (int c = 0; c < NCLS; ++c) {
        float s = 0.f;
#pragma unroll
        for (int t = 0; t < 21; ++t) s += u[t] * H[t * NCLS + c];
        float h = (s + ba * v[c]) * inv + w[c];
        out[b * NCLS + c] = (h >= 0.f) ? h : 0.2f * h;
    }
}

extern "C" void kernel_launch(void* const* d_in, const int* in_sizes, int n_in,
                              void* d_out, int out_size, void* d_ws, size_t ws_size,
                              hipStream_t stream) {
    const float* x    = (const float*)d_in[0];
    const float* c    = (const float*)d_in[1];
    const float* bbv  = (const float*)d_in[2];
    const float* wei  = (const float*)d_in[3];
    const float* bais = (const float*)d_in[4];
    const float* W1   = (const float*)d_in[5];
    const float* b1   = (const float*)d_in[6];
    const float* W2   = (const float*)d_in[7];
    const float* b2   = (const float*)d_in[8];
    const float* W3   = (const float*)d_in[9];
    const float* b3   = (const float*)d_in[10];

    float* ws  = (float*)d_ws;
    float* S   = ws;                         // 21*SSTR
    float* G   = S + 21 * SSTR;              // 21*SSTR
    float* SW1 = G + 21 * SSTR;              // 21*512
    float* ws1 = SW1 + 21 * MID;             // 512
    float* q   = ws1 + MID;                  // SSTR
    float* p   = q + SSTR;                   // SSTR
    float* T   = p + SSTR;                   // 32
    float* H   = T + 32;                     // 224 (21*10 used)
    float* v   = H + 224;                    // 16
    float* w   = v + 16;                     // 16

    hipMemsetAsync(S, 0, (size_t)(21 * SSTR) * sizeof(float), stream);
    k_reduce_wei<<<dim3(9, 81), 256, 0, stream>>>(wei, S);
    k_sw1<<<MID, 64, 0, stream>>>(S, W1, SW1, ws1);
    k_g<<<FUZZ, 64, 0, stream>>>(SW1, ws1, b1, W2, G, q, p);
    k_h<<<NCLS + 1, 64, 0, stream>>>(S, G, q, p, b2, b3, W3, H, v, w, T);
    k_out<<<(BATCH + 255) / 256, 256, 0, stream>>>(x, c, bbv, bais, T, H, v, w,
                                                   (float*)d_out);
}